// Round 5
// baseline (966.353 us; speedup 1.0000x reference)
//
#include <hip/hip_runtime.h>
#include <stdint.h>

typedef unsigned short u16;
typedef short short8 __attribute__((ext_vector_type(8)));
typedef float f32x4 __attribute__((ext_vector_type(4)));

__device__ __forceinline__ float b2f(u16 u) { return __uint_as_float(((uint32_t)u) << 16); }
__device__ __forceinline__ u16 f2b(float f) {
    uint32_t x = __float_as_uint(f);
    uint32_t r = x + 0x7fffu + ((x >> 16) & 1u);
    return (u16)(r >> 16);
}

// Load 8 contiguous elements as bf16 into dst. F32: convert from float32.
template <bool F32>
__device__ __forceinline__ void ld8(const void* p, size_t eoff, u16* dst) {
    if constexpr (F32) {
        const float* q = (const float*)p + eoff;
        float4 a = *(const float4*)q;
        float4 b = *(const float4*)(q + 4);
        dst[0] = f2b(a.x); dst[1] = f2b(a.y); dst[2] = f2b(a.z); dst[3] = f2b(a.w);
        dst[4] = f2b(b.x); dst[5] = f2b(b.y); dst[6] = f2b(b.z); dst[7] = f2b(b.w);
    } else {
        *(int4*)dst = *(const int4*)((const u16*)p + eoff);
    }
}

// ---------------------------------------------------------------------------
// Generic MFMA GEMM: C(M,N) = A(M,K) @ B(N,K)^T (+bias f32) with epilogues.
// A: bf16 (AF32=0) or f32 (AF32=1); B likewise. 128x128 tile, 256 thr, BK=32.
// MODE 0: out_b = [relu](acc+bias)                     (bf16 store)
// MODE 1: out_f = acc+bias                             (f32 store)
// MODE 2: out_f += acc+bias                            (f32 accumulate)
// MODE 3: t = acc+bias+res_f; out_f = t; out_b = t     (residual, both)
// MODE 4: t = 0.5*(acc + res_f); out_f = t
// MODE 5: t = acc+bias+res_f; out_f = t                (f32 store)
// ---------------------------------------------------------------------------
template <int MODE, bool RELU, bool AF32, bool BF32>
__global__ __launch_bounds__(256) void gemm_k(
    const void* __restrict__ A, int lda,
    const void* __restrict__ B, int ldb,
    const float* __restrict__ bias,
    int M, int N, int K,
    u16* __restrict__ out_b, float* __restrict__ out_f,
    const float* __restrict__ res_f)
{
    const int tn = blockIdx.x, tm = blockIdx.y;
    const int tid = threadIdx.x;
    const int wave = tid >> 6, lane = tid & 63;
    const int quad = lane >> 4, mm = lane & 15;
    const int wr = (wave >> 1) * 64, wc = (wave & 1) * 64;

    __shared__ __align__(16) u16 As[128 * 32];
    __shared__ __align__(16) u16 Bs[128 * 32];

    const f32x4 vzero = {0.f, 0.f, 0.f, 0.f};
    f32x4 acc[4][4];
#pragma unroll
    for (int i = 0; i < 4; i++)
#pragma unroll
        for (int j = 0; j < 4; j++) acc[i][j] = vzero;

    const int lr = tid >> 2;        // 0..63
    const int lc = (tid & 3) * 8;   // 0,8,16,24
    const size_t abase0 = (size_t)(tm * 128 + lr) * lda + lc;
    const size_t abase1 = (size_t)(tm * 128 + lr + 64) * lda + lc;
    const size_t bbase0 = (size_t)(tn * 128 + lr) * ldb + lc;
    const size_t bbase1 = (size_t)(tn * 128 + lr + 64) * ldb + lc;

    for (int kt = 0; kt < K; kt += 32) {
        __align__(16) u16 a0[8], a1[8], b0[8], b1[8];
        ld8<AF32>(A, abase0 + kt, a0);
        ld8<AF32>(A, abase1 + kt, a1);
        ld8<BF32>(B, bbase0 + kt, b0);
        ld8<BF32>(B, bbase1 + kt, b1);
        __syncthreads();
        *(int4*)(As + lr * 32 + lc) = *(const int4*)a0;
        *(int4*)(As + (lr + 64) * 32 + lc) = *(const int4*)a1;
        *(int4*)(Bs + lr * 32 + lc) = *(const int4*)b0;
        *(int4*)(Bs + (lr + 64) * 32 + lc) = *(const int4*)b1;
        __syncthreads();
        short8 af[4], bfr[4];
#pragma unroll
        for (int i = 0; i < 4; i++) af[i] = *(const short8*)(As + (wr + i * 16 + mm) * 32 + quad * 8);
#pragma unroll
        for (int j = 0; j < 4; j++) bfr[j] = *(const short8*)(Bs + (wc + j * 16 + mm) * 32 + quad * 8);
#pragma unroll
        for (int i = 0; i < 4; i++)
#pragma unroll
            for (int j = 0; j < 4; j++)
                acc[i][j] = __builtin_amdgcn_mfma_f32_16x16x32_bf16(af[i], bfr[j], acc[i][j], 0, 0, 0);
    }

#pragma unroll
    for (int j = 0; j < 4; j++) {
        const int colg = tn * 128 + wc + j * 16 + mm;
        const float bv = bias ? bias[colg] : 0.f;
#pragma unroll
        for (int i = 0; i < 4; i++) {
#pragma unroll
            for (int r = 0; r < 4; r++) {
                const int rowg = tm * 128 + wr + i * 16 + quad * 4 + r;
                float v = acc[i][j][r] + bv;
                const size_t off = (size_t)rowg * N + colg;
                if constexpr (MODE == 0) {
                    if (RELU) v = fmaxf(v, 0.f);
                    out_b[off] = f2b(v);
                } else if constexpr (MODE == 1) {
                    out_f[off] = v;
                } else if constexpr (MODE == 2) {
                    out_f[off] += v;
                } else if constexpr (MODE == 3) {
                    v += res_f[off];
                    out_f[off] = v;
                    out_b[off] = f2b(v);
                } else if constexpr (MODE == 4) {
                    v = 0.5f * (v + res_f[off]);
                    out_f[off] = v;
                } else {  // MODE 5: f32 store with residual
                    v += res_f[off];
                    out_f[off] = v;
                }
            }
        }
    }
}

// ---------------------------------------------------------------------------
// Flash attention: one wave per (q-tile of 64, b, h). Causal, online softmax.
// QKV layout: [(s*16+b)*1536 + {0,512,1024} + h*64 + d] (bf16). Out: (S,B,E).
// ---------------------------------------------------------------------------
__global__ __launch_bounds__(64) void attn_k(const u16* __restrict__ QKV, u16* __restrict__ O)
{
    const int qt = blockIdx.x;   // 0..7
    const int bh = blockIdx.y;   // 0..127
    const int b = bh >> 3, h = bh & 7;
    const int lane = threadIdx.x;
    const int quad = lane >> 4, mm = lane & 15;
    const int cbase = h * 64;
    const float NEGINF = -3.0e38f;

    __shared__ __align__(16) u16 Pl[64 * 72];
    __shared__ __align__(16) u16 Vl[64 * 72];

    short8 qf[4][2];
#pragma unroll
    for (int rt = 0; rt < 4; ++rt) {
        const int s = qt * 64 + rt * 16 + mm;
        const u16* p = QKV + ((size_t)s * 16 + b) * 1536 + cbase + quad * 8;
        qf[rt][0] = *(const short8*)(p);
        qf[rt][1] = *(const short8*)(p + 32);
    }

    const f32x4 vzero = {0.f, 0.f, 0.f, 0.f};
    f32x4 of[4][4];
#pragma unroll
    for (int i = 0; i < 4; i++)
#pragma unroll
        for (int j = 0; j < 4; j++) of[i][j] = vzero;
    float mrow[4][4], lrow[4][4];
#pragma unroll
    for (int i = 0; i < 4; i++)
#pragma unroll
        for (int r = 0; r < 4; r++) { mrow[i][r] = NEGINF; lrow[i][r] = 0.f; }

    for (int kt = 0; kt <= qt; ++kt) {
        short8 kf[4][2];
#pragma unroll
        for (int nt = 0; nt < 4; ++nt) {
            const int kk = kt * 64 + nt * 16 + mm;
            const u16* p = QKV + ((size_t)kk * 16 + b) * 1536 + 512 + cbase + quad * 8;
            kf[nt][0] = *(const short8*)(p);
            kf[nt][1] = *(const short8*)(p + 32);
        }
        f32x4 sf[4][4];
#pragma unroll
        for (int i = 0; i < 4; i++)
#pragma unroll
            for (int j = 0; j < 4; j++) sf[i][j] = vzero;
#pragma unroll
        for (int i = 0; i < 4; i++)
#pragma unroll
            for (int j = 0; j < 4; j++) {
                sf[i][j] = __builtin_amdgcn_mfma_f32_16x16x32_bf16(qf[i][0], kf[j][0], sf[i][j], 0, 0, 0);
                sf[i][j] = __builtin_amdgcn_mfma_f32_16x16x32_bf16(qf[i][1], kf[j][1], sf[i][j], 0, 0, 0);
            }
        {
            const int kk = lane >> 3, c8 = (lane & 7) * 8;
#pragma unroll
            for (int it = 0; it < 8; ++it) {
                const int key = kt * 64 + it * 8 + kk;
                int4 v = *(const int4*)(QKV + ((size_t)key * 16 + b) * 1536 + 1024 + cbase + c8);
                *(int4*)(Vl + (it * 8 + kk) * 72 + c8) = v;
            }
        }
        const bool diag = (kt == qt);
#pragma unroll
        for (int i = 0; i < 4; i++)
#pragma unroll
            for (int j = 0; j < 4; j++)
#pragma unroll
                for (int r = 0; r < 4; r++) {
                    float v = sf[i][j][r] * 0.125f;
                    if (diag) {
                        const int q = i * 16 + quad * 4 + r;
                        const int k = j * 16 + mm;
                        if (k > q) v = NEGINF;
                    }
                    sf[i][j][r] = v;
                }
#pragma unroll
        for (int i = 0; i < 4; i++) {
#pragma unroll
            for (int r = 0; r < 4; r++) {
                float mx = fmaxf(fmaxf(sf[i][0][r], sf[i][1][r]), fmaxf(sf[i][2][r], sf[i][3][r]));
                mx = fmaxf(mx, __shfl_xor(mx, 1));
                mx = fmaxf(mx, __shfl_xor(mx, 2));
                mx = fmaxf(mx, __shfl_xor(mx, 4));
                mx = fmaxf(mx, __shfl_xor(mx, 8));
                const float mnew = fmaxf(mrow[i][r], mx);
                const float alpha = __expf(mrow[i][r] - mnew);
                mrow[i][r] = mnew;
                float psum = 0.f;
#pragma unroll
                for (int j = 0; j < 4; j++) {
                    float p = __expf(sf[i][j][r] - mnew);
                    sf[i][j][r] = p;
                    psum += p;
                }
                psum += __shfl_xor(psum, 1);
                psum += __shfl_xor(psum, 2);
                psum += __shfl_xor(psum, 4);
                psum += __shfl_xor(psum, 8);
                lrow[i][r] = lrow[i][r] * alpha + psum;
#pragma unroll
                for (int j = 0; j < 4; j++) of[i][j][r] *= alpha;
            }
        }
#pragma unroll
        for (int i = 0; i < 4; i++)
#pragma unroll
            for (int j = 0; j < 4; j++)
#pragma unroll
                for (int r = 0; r < 4; r++)
                    Pl[(i * 16 + quad * 4 + r) * 72 + j * 16 + mm] = f2b(sf[i][j][r]);
        __syncthreads();
        short8 pa[4][2];
#pragma unroll
        for (int i = 0; i < 4; i++) {
            pa[i][0] = *(const short8*)(Pl + (i * 16 + mm) * 72 + quad * 8);
            pa[i][1] = *(const short8*)(Pl + (i * 16 + mm) * 72 + 32 + quad * 8);
        }
#pragma unroll
        for (int j = 0; j < 4; j++) {
#pragma unroll
            for (int kc = 0; kc < 2; ++kc) {
                short8 vb;
#pragma unroll
                for (int e = 0; e < 8; e++)
                    vb[e] = (short)Vl[(kc * 32 + quad * 8 + e) * 72 + j * 16 + mm];
#pragma unroll
                for (int i = 0; i < 4; i++)
                    of[i][j] = __builtin_amdgcn_mfma_f32_16x16x32_bf16(pa[i][kc], vb, of[i][j], 0, 0, 0);
            }
        }
        __syncthreads();
    }
#pragma unroll
    for (int i = 0; i < 4; i++)
#pragma unroll
        for (int r = 0; r < 4; r++) {
            const int s = qt * 64 + i * 16 + quad * 4 + r;
            const float inv = 1.f / lrow[i][r];
#pragma unroll
            for (int j = 0; j < 4; j++)
                O[((size_t)s * 16 + b) * 512 + cbase + j * 16 + mm] = f2b(of[i][j][r] * inv);
        }
}

// ---------------------------------------------------------------------------
// LayerNorm over E=512, f32 input, f32 gain/bias, bf16 output. 1 wave/row.
// ---------------------------------------------------------------------------
__global__ __launch_bounds__(256) void ln_k(const float* __restrict__ x,
                                            const float* __restrict__ g,
                                            const float* __restrict__ be,
                                            u16* __restrict__ out)
{
    const int row = blockIdx.x * 4 + (threadIdx.x >> 6);
    const int lane = threadIdx.x & 63;
    const float* p = x + (size_t)row * 512 + lane * 8;
    float4 u0 = *(const float4*)p;
    float4 u1 = *(const float4*)(p + 4);
    float v[8] = {u0.x, u0.y, u0.z, u0.w, u1.x, u1.y, u1.z, u1.w};
    float s = 0.f, s2 = 0.f;
#pragma unroll
    for (int j = 0; j < 8; j++) { s += v[j]; s2 += v[j] * v[j]; }
#pragma unroll
    for (int off = 1; off < 64; off <<= 1) { s += __shfl_xor(s, off); s2 += __shfl_xor(s2, off); }
    const float mean = s * (1.f / 512.f);
    const float var = s2 * (1.f / 512.f) - mean * mean;
    const float rstd = rsqrtf(fmaxf(var, 0.f) + 1e-5f);
    float4 g0 = *(const float4*)(g + lane * 8);
    float4 g1 = *(const float4*)(g + lane * 8 + 4);
    float4 b0 = *(const float4*)(be + lane * 8);
    float4 b1 = *(const float4*)(be + lane * 8 + 4);
    const float gg[8] = {g0.x, g0.y, g0.z, g0.w, g1.x, g1.y, g1.z, g1.w};
    const float bb[8] = {b0.x, b0.y, b0.z, b0.w, b1.x, b1.y, b1.z, b1.w};
    __align__(16) u16 o[8];
#pragma unroll
    for (int j = 0; j < 8; j++)
        o[j] = f2b((v[j] - mean) * rstd * gg[j] + bb[j]);
    *(int4*)(out + (size_t)row * 512 + lane * 8) = *(const int4*)o;
}

// nonsat: Newton for y^3/3 + y = x, 14 fixed iterations. f32 in, f32 out.
__global__ __launch_bounds__(256) void nonsat_k(const float* __restrict__ in, float* __restrict__ out, int n)
{
    const int i = blockIdx.x * 256 + threadIdx.x;
    if (i >= n) return;
    const float x = in[i];
    float y = x;
#pragma unroll
    for (int t = 0; t < 14; ++t) {
        const float y2 = y * y;
        y = (0.66666667f * y2 * y + x) / (y2 + 1.f);
    }
    out[i] = y;
}

// X1b (row = s*16+b) -> XB (row = b*512+s), bf16
__global__ __launch_bounds__(64) void transp_k(const u16* __restrict__ X, u16* __restrict__ Y)
{
    const int r = blockIdx.x;
    const int b = r >> 9, s = r & 511;
    const int lane = threadIdx.x;
    *(int4*)(Y + (size_t)r * 512 + lane * 8) =
        *(const int4*)(X + (size_t)(s * 16 + b) * 512 + lane * 8);
}

// VX[r_sb] = [X1b[r_sb] (512 bf16), bf16(Hb_f32[b*512+s]) (512)]
__global__ __launch_bounds__(128) void vxpack_k(const u16* __restrict__ Xb, const float* __restrict__ Hb,
                                                u16* __restrict__ VX)
{
    const int r = blockIdx.x;
    const int lane = threadIdx.x;
    const int s = r >> 4, b = r & 15;
    if (lane < 64) {
        *(int4*)(VX + (size_t)r * 1024 + lane * 8) =
            *(const int4*)(Xb + (size_t)r * 512 + lane * 8);
    } else {
        const int l = lane - 64;
        const float* p = Hb + ((size_t)b * 512 + s) * 512 + l * 8;
        float4 a = *(const float4*)p;
        float4 c = *(const float4*)(p + 4);
        __align__(16) u16 o[8] = {f2b(a.x), f2b(a.y), f2b(a.z), f2b(a.w),
                                  f2b(c.x), f2b(c.y), f2b(c.z), f2b(c.w)};
        *(int4*)(VX + (size_t)r * 1024 + 512 + l * 8) = *(const int4*)o;
    }
}

// softmax over 128 per row, f32 in -> bf16 out. One wave per row.
__global__ __launch_bounds__(256) void softmax128_k(const float* __restrict__ in, u16* __restrict__ out)
{
    const int row = blockIdx.x * 4 + (threadIdx.x >> 6);
    const int lane = threadIdx.x & 63;
    const float* p = in + (size_t)row * 128;
    const float a = p[lane], b = p[lane + 64];
    float mx = fmaxf(a, b);
#pragma unroll
    for (int off = 1; off < 64; off <<= 1) mx = fmaxf(mx, __shfl_xor(mx, off));
    const float ea = __expf(a - mx), eb = __expf(b - mx);
    float s = ea + eb;
#pragma unroll
    for (int off = 1; off < 64; off <<= 1) s += __shfl_xor(s, off);
    const float inv = 1.f / s;
    out[(size_t)row * 128 + lane] = f2b(ea * inv);
    out[(size_t)row * 128 + 64 + lane] = f2b(eb * inv);
}

// controls = softmax(hidden @ A_w^T + A_b) over 3. H f32, A_w/A_b f32.
__global__ __launch_bounds__(256) void controls_k(const float* __restrict__ H, const float* __restrict__ Aw,
                                                  const float* __restrict__ Ab, float* __restrict__ ctrl)
{
    const int row = blockIdx.x * 4 + (threadIdx.x >> 6);
    const int lane = threadIdx.x & 63;
    const float* hp = H + (size_t)row * 512 + lane * 8;
    float4 h0 = *(const float4*)hp;
    float4 h1 = *(const float4*)(hp + 4);
    const float hv[8] = {h0.x, h0.y, h0.z, h0.w, h1.x, h1.y, h1.z, h1.w};
    float d[3];
#pragma unroll
    for (int w = 0; w < 3; ++w) {
        const float* ap = Aw + w * 512 + lane * 8;
        float4 a0 = *(const float4*)ap;
        float4 a1 = *(const float4*)(ap + 4);
        const float av[8] = {a0.x, a0.y, a0.z, a0.w, a1.x, a1.y, a1.z, a1.w};
        float acc = 0.f;
#pragma unroll
        for (int j = 0; j < 8; j++) acc += hv[j] * av[j];
        d[w] = acc;
    }
#pragma unroll
    for (int off = 1; off < 64; off <<= 1) {
        d[0] += __shfl_xor(d[0], off);
        d[1] += __shfl_xor(d[1], off);
        d[2] += __shfl_xor(d[2], off);
    }
    const float l0 = d[0] + Ab[0], l1 = d[1] + Ab[1], l2 = d[2] + Ab[2];
    const float mx = fmaxf(l0, fmaxf(l1, l2));
    const float e0 = __expf(l0 - mx), e1 = __expf(l1 - mx), e2 = __expf(l2 - mx);
    const float inv = 1.f / (e0 + e1 + e2);
    if (lane == 0) {
        ctrl[(size_t)row * 3 + 0] = e0 * inv;
        ctrl[(size_t)row * 3 + 1] = e1 * inv;
        ctrl[(size_t)row * 3 + 2] = e2 * inv;
    }
}

// stack = a_noop*prev + a_push*up + a_pop*down. All f32.
__global__ __launch_bounds__(256) void stack_k(const float* __restrict__ sp_all, const float* __restrict__ sin,
                                               const float* __restrict__ ctrl, float* __restrict__ out)
{
    const int bs = blockIdx.x;
    const int t = blockIdx.y * 256 + threadIdx.x;  // 0..767
    const int d = t >> 4;
    const int w = (t & 15) * 8;
    const float* sp = sp_all + (size_t)bs * 6144;
    const float pu = ctrl[(size_t)bs * 3 + 0];
    const float po = ctrl[(size_t)bs * 3 + 1];
    const float no = ctrl[(size_t)bs * 3 + 2];
    float cur[8], up[8], dn[8];
    {
        const float* p = sp + d * 128 + w;
        float4 c0 = *(const float4*)p, c1 = *(const float4*)(p + 4);
        cur[0]=c0.x; cur[1]=c0.y; cur[2]=c0.z; cur[3]=c0.w; cur[4]=c1.x; cur[5]=c1.y; cur[6]=c1.z; cur[7]=c1.w;
    }
    {
        const float* p = (d == 0) ? (sin + (size_t)bs * 128 + w) : (sp + (d - 1) * 128 + w);
        float4 c0 = *(const float4*)p, c1 = *(const float4*)(p + 4);
        up[0]=c0.x; up[1]=c0.y; up[2]=c0.z; up[3]=c0.w; up[4]=c1.x; up[5]=c1.y; up[6]=c1.z; up[7]=c1.w;
    }
    if (d < 47) {
        const float* p = sp + (d + 1) * 128 + w;
        float4 c0 = *(const float4*)p, c1 = *(const float4*)(p + 4);
        dn[0]=c0.x; dn[1]=c0.y; dn[2]=c0.z; dn[3]=c0.w; dn[4]=c1.x; dn[5]=c1.y; dn[6]=c1.z; dn[7]=c1.w;
    } else {
#pragma unroll
        for (int j = 0; j < 8; j++) dn[j] = 0.f;
    }
    float o[8];
#pragma unroll
    for (int j = 0; j < 8; j++)
        o[j] = no * cur[j] + pu * up[j] + po * dn[j];
    float* q = out + (size_t)bs * 6144 + d * 128 + w;
    *(float4*)q = make_float4(o[0], o[1], o[2], o[3]);
    *(float4*)(q + 4) = make_float4(o[4], o[5], o[6], o[7]);
}

// ---------------------------------------------------------------------------
// Workspace layout (bytes), total 100 MB with aliasing.
// ---------------------------------------------------------------------------
static constexpr size_t O_A1 = 0;                        // bf16 8192x512  (later: X1B)
static constexpr size_t O_QKV = O_A1 + 8388608;          // bf16 8192x1536 (later: VX/PS/SIN/CTRL)
static constexpr size_t O_OATT = O_QKV + 25165824;       // bf16 8192x512  (later: XB)
static constexpr size_t O_X1F = O_OATT + 8388608;        // f32 8192x512   (later: FF1 lower half)
static constexpr size_t O_HPF = O_X1F + 16777216;        // f32 8192x512   (later: FF1 upper half)
static constexpr size_t O_VL = O_HPF + 16777216;         // f32 8192x128   (later: SINP)
static constexpr size_t O_X2F = O_VL + 4194304;          // f32 8192x512
static constexpr size_t O_H2 = O_X2F + 16777216;         // bf16 8192x512
static constexpr size_t WS_NEED = O_H2 + 8388608;        // 104,857,600
static constexpr size_t O_VX = O_QKV;                    // bf16 8192x1024
static constexpr size_t O_PS = O_QKV + 16777216;         // bf16 8192x128
static constexpr size_t O_SIN = O_QKV + 18874368;        // f32  8192x128 (4 MB)
static constexpr size_t O_CTRL = O_QKV + 23068672;       // f32  8192x3
static constexpr size_t O_XB = O_OATT;                   // bf16 8192x512
static constexpr size_t O_X1B = O_A1;                    // bf16 8192x512
static constexpr size_t O_FF1 = O_X1F;                   // bf16 8192x2048
static constexpr size_t O_SINP = O_VL;                   // f32  8192x128

extern "C" void kernel_launch(void* const* d_in, const int* in_sizes, int n_in,
                              void* d_out, int out_size, void* d_ws, size_t ws_size,
                              hipStream_t stream)
{
    (void)in_sizes; (void)n_in; (void)out_size;
    if (ws_size < WS_NEED) return;

    const float* x_in        = (const float*)d_in[0];
    const float* hidden_prev = (const float*)d_in[1];
    const float* stack_prev  = (const float*)d_in[2];
    // d_in[3] = k_mask (all false) — unused
    const float* in_proj_w   = (const float*)d_in[4];
    const float* in_proj_b   = (const float*)d_in[5];
    const float* out_proj_w  = (const float*)d_in[6];
    const float* out_proj_b  = (const float*)d_in[7];
    const float* ln1_g       = (const float*)d_in[8];
    const float* ln1_b       = (const float*)d_in[9];
    const float* ln2_g       = (const float*)d_in[10];
    const float* ln2_b       = (const float*)d_in[11];
    const float* ff_w1       = (const float*)d_in[12];
    const float* ff_b1       = (const float*)d_in[13];
    const float* ff_w2       = (const float*)d_in[14];
    const float* ff_b2       = (const float*)d_in[15];
    const float* W_w         = (const float*)d_in[16];
    const float* W_b         = (const float*)d_in[17];
    const float* R_w         = (const float*)d_in[18];
    const float* R_b         = (const float*)d_in[19];
    const float* P_w         = (const float*)d_in[20];
    const float* P_b         = (const float*)d_in[21];
    const float* V_w         = (const float*)d_in[22];
    const float* U_w         = (const float*)d_in[23];
    const float* A_w         = (const float*)d_in[24];
    const float* A_b         = (const float*)d_in[25];
    const float* D_w         = (const float*)d_in[26];
    const float* D_b         = (const float*)d_in[27];

    char* ws = (char*)d_ws;
    u16* A1   = (u16*)(ws + O_A1);
    u16* QKV  = (u16*)(ws + O_QKV);
    u16* OATT = (u16*)(ws + O_OATT);
    float* X1F = (float*)(ws + O_X1F);
    float* HPF = (float*)(ws + O_HPF);
    float* VL  = (float*)(ws + O_VL);
    float* X2F = (float*)(ws + O_X2F);
    u16* H2   = (u16*)(ws + O_H2);
    u16* VX   = (u16*)(ws + O_VX);
    u16* PS   = (u16*)(ws + O_PS);
    float* SIN = (float*)(ws + O_SIN);
    float* CTRL = (float*)(ws + O_CTRL);
    u16* XB   = (u16*)(ws + O_XB);
    u16* X1B  = (u16*)(ws + O_X1B);
    u16* FF1  = (u16*)(ws + O_FF1);
    float* SINP = (float*)(ws + O_SINP);

    float* out = (float*)d_out;
    float* x_out = out;                       // (S,B,E) f32
    float* hid_out = out + 4194304;           // (B,S,512) f32
    float* stack_out = out + 8388608;         // (B,S,48,128) f32

    // 1. LN1 (f32 in -> bf16)
    ln_k<<<2048, 256, 0, stream>>>(x_in, ln1_g, ln1_b, A1);
    // 2. QKV = ln1 @ in_proj^T + b
    gemm_k<0, false, false, true><<<dim3(12, 64), 256, 0, stream>>>(
        A1, 512, in_proj_w, 512, in_proj_b, 8192, 1536, 512, QKV, nullptr, nullptr);
    // 3. attention
    attn_k<<<dim3(8, 128), 64, 0, stream>>>(QKV, OATT);
    // 4. x = x_in + attn @ out_proj^T + b   (store f32 + bf16)
    gemm_k<3, false, false, true><<<dim3(4, 64), 256, 0, stream>>>(
        OATT, 512, out_proj_w, 512, out_proj_b, 8192, 512, 512, X1B, X1F, x_in);
    // 5. XB = x transposed to (B,S,E)
    transp_k<<<8192, 64, 0, stream>>>(X1B, XB);
    // 6. hidden_pre = XB@W^T + W_b + hidden_prev@R^T + R_b + stack_x@P^T + P_b
    gemm_k<1, false, false, true><<<dim3(4, 64), 256, 0, stream>>>(
        XB, 512, W_w, 512, W_b, 8192, 512, 512, nullptr, HPF, nullptr);
    gemm_k<2, false, true, true><<<dim3(4, 64), 256, 0, stream>>>(
        hidden_prev, 512, R_w, 512, R_b, 8192, 512, 512, nullptr, HPF, nullptr);
    gemm_k<2, false, true, true><<<dim3(4, 64), 256, 0, stream>>>(
        stack_prev, 6144, P_w, 128, P_b, 8192, 512, 128, nullptr, HPF, nullptr);
    // 7. hidden = nonsat(hidden_pre) -> d_out hidden region (f32)
    nonsat_k<<<16384, 256, 0, stream>>>(HPF, hid_out, 4194304);
    // 8. VX = [x, hidden^T]
    vxpack_k<<<8192, 128, 0, stream>>>(X1B, hid_out, VX);
    // 9. VL = VX @ V_w^T ; PS = softmax(VL)
    gemm_k<1, false, false, true><<<dim3(1, 64), 256, 0, stream>>>(
        VX, 1024, V_w, 1024, nullptr, 8192, 128, 1024, nullptr, VL, nullptr);
    softmax128_k<<<2048, 256, 0, stream>>>(VL, PS);
    // 10. x2 = 0.5*(x + PS @ U_w^T)
    gemm_k<4, false, false, true><<<dim3(4, 64), 256, 0, stream>>>(
        PS, 128, U_w, 128, nullptr, 8192, 512, 128, nullptr, X2F, X1F);
    // 11. stack_inp = nonsat(hidden @ D_w^T + D_b)  (hidden now f32)
    gemm_k<1, false, true, true><<<dim3(1, 64), 256, 0, stream>>>(
        hid_out, 512, D_w, 512, D_b, 8192, 128, 512, nullptr, SINP, nullptr);
    nonsat_k<<<4096, 256, 0, stream>>>(SINP, SIN, 1048576);
    // 12. controls
    controls_k<<<2048, 256, 0, stream>>>(hid_out, A_w, A_b, CTRL);
    // 13. stack update -> d_out (f32)
    stack_k<<<dim3(8192, 3), 256, 0, stream>>>(stack_prev, SIN, CTRL, stack_out);
    // 14. h = LN2(x2)
    ln_k<<<2048, 256, 0, stream>>>(X2F, ln2_g, ln2_b, H2);
    // 15. FF1 = relu(h @ ff_w1^T + b1)
    gemm_k<0, true, false, true><<<dim3(16, 64), 256, 0, stream>>>(
        H2, 512, ff_w1, 512, ff_b1, 8192, 2048, 512, FF1, nullptr, nullptr);
    // 16. x_out = x2 + FF1 @ ff_w2^T + b2 -> d_out (f32)
    gemm_k<5, false, false, true><<<dim3(4, 64), 256, 0, stream>>>(
        FF1, 2048, ff_w2, 2048, ff_b2, 8192, 512, 2048, nullptr, x_out, X2F);
}